// Round 1
// baseline (1525.458 us; speedup 1.0000x reference)
//
#include <hip/hip_runtime.h>
#include <type_traits>
#include <cstdint>

// Problem constants
constexpr int Cc = 95;    // input channels
constexpr int Hh = 128;   // hidden
constexpr int G  = 512;   // 4*H gates
constexpr int Bb = 256;   // batch
constexpr int Tt = 1000;  // timesteps
#define EPSBN 1e-5f

__device__ __forceinline__ float fsig(float x) {
  x = fminf(20.f, fmaxf(-20.f, x));
  return 1.f / (1.f + __expf(-x));
}
__device__ __forceinline__ float ftanh_(float x) {
  x = fminf(20.f, fmaxf(-20.f, x));
  float e = __expf(-2.f * x);
  return (1.f - e) / (1.f + e);
}

// ---------------------------------------------------------------------------
// K1: xw[m][g] = BN(x[b, t0+tl, :]) . W_ih[g, :] + (b_ih[g] + b_hh[g])
//     m = b*TC + tl (chunk-local row), 64x64 output tile per block, K=95 whole.
// ---------------------------------------------------------------------------
template <int TC>
__global__ __launch_bounds__(256)
void k1_gemm(const float* __restrict__ x, const float* __restrict__ gamma,
             const float* __restrict__ beta, const float* __restrict__ rmean,
             const float* __restrict__ rvar, const float* __restrict__ W_ih,
             const float* __restrict__ b_ih, const float* __restrict__ b_hh,
             float* __restrict__ xw, int t0) {
  // stride-65 pad: bank = (c + r) % 32 -> conflict-free transpose writes
  __shared__ float As[Cc][65];
  __shared__ float Ws[Cc][65];
  __shared__ float scl[Cc], sft[Cc];

  const int tid = threadIdx.x;
  if (tid < Cc) {
    float s = gamma[tid] * rsqrtf(rvar[tid] + EPSBN);
    scl[tid] = s;
    sft[tid] = beta[tid] - rmean[tid] * s;
  }
  __syncthreads();

  const int row0 = blockIdx.x * 64;  // chunk-local xn row
  const int col0 = blockIdx.y * 64;  // gate column

  // Stage A (64 rows x 95 ch, BN applied) and W (64 gates x 95) transposed.
  for (int idx = tid; idx < 64 * Cc; idx += 256) {
    int r = idx / Cc;
    int c = idx - r * Cc;
    int m = row0 + r;
    int b = m / TC;
    int tl = m - b * TC;
    float v = x[((size_t)b * Tt + t0 + tl) * Cc + c];
    As[c][r] = v * scl[c] + sft[c];
    Ws[c][r] = W_ih[(size_t)(col0 + r) * Cc + c];
  }
  __syncthreads();

  const int tx = tid & 15, ty = tid >> 4;
  const int ai = ty * 4, wi = tx * 4;
  float acc[4][4];
#pragma unroll
  for (int i = 0; i < 4; ++i)
#pragma unroll
    for (int j = 0; j < 4; ++j) acc[i][j] = 0.f;

#pragma unroll 5
  for (int k = 0; k < Cc; ++k) {
    float a0 = As[k][ai + 0], a1 = As[k][ai + 1];
    float a2 = As[k][ai + 2], a3 = As[k][ai + 3];
    float w0 = Ws[k][wi + 0], w1 = Ws[k][wi + 1];
    float w2 = Ws[k][wi + 2], w3 = Ws[k][wi + 3];
    acc[0][0] = fmaf(a0, w0, acc[0][0]); acc[0][1] = fmaf(a0, w1, acc[0][1]);
    acc[0][2] = fmaf(a0, w2, acc[0][2]); acc[0][3] = fmaf(a0, w3, acc[0][3]);
    acc[1][0] = fmaf(a1, w0, acc[1][0]); acc[1][1] = fmaf(a1, w1, acc[1][1]);
    acc[1][2] = fmaf(a1, w2, acc[1][2]); acc[1][3] = fmaf(a1, w3, acc[1][3]);
    acc[2][0] = fmaf(a2, w0, acc[2][0]); acc[2][1] = fmaf(a2, w1, acc[2][1]);
    acc[2][2] = fmaf(a2, w2, acc[2][2]); acc[2][3] = fmaf(a2, w3, acc[2][3]);
    acc[3][0] = fmaf(a3, w0, acc[3][0]); acc[3][1] = fmaf(a3, w1, acc[3][1]);
    acc[3][2] = fmaf(a3, w2, acc[3][2]); acc[3][3] = fmaf(a3, w3, acc[3][3]);
  }

  float bi0 = b_ih[col0 + wi + 0] + b_hh[col0 + wi + 0];
  float bi1 = b_ih[col0 + wi + 1] + b_hh[col0 + wi + 1];
  float bi2 = b_ih[col0 + wi + 2] + b_hh[col0 + wi + 2];
  float bi3 = b_ih[col0 + wi + 3] + b_hh[col0 + wi + 3];
#pragma unroll
  for (int i = 0; i < 4; ++i) {
    size_t m = (size_t)(row0 + ai + i);
    float4 v = make_float4(acc[i][0] + bi0, acc[i][1] + bi1,
                           acc[i][2] + bi2, acc[i][3] + bi3);
    *reinterpret_cast<float4*>(&xw[m * G + col0 + wi]) = v;
  }
}

// ---------------------------------------------------------------------------
// K2: per-batch-element LSTM recurrence. 256 blocks x 512 threads.
// Thread g owns W_hh row g (128 VGPRs). h in LDS; c in regs of threads 0..127.
// ---------------------------------------------------------------------------
template <int TC>
__global__ __launch_bounds__(512, 2)
void k2_lstm(const float* __restrict__ xw, const float* __restrict__ W_hh,
             float* __restrict__ hstate, float* __restrict__ cstate,
             const float* __restrict__ fc_w, const float* __restrict__ fc_b,
             float* __restrict__ out, int t0) {
  __shared__ __align__(16) float h_lds[Hh];
  __shared__ float gl[G];

  const int b = blockIdx.x;
  const int g = threadIdx.x;

  // W_hh row -> registers (one-time; W_hh is 256 KB, L2/L3 resident)
  float4 w4[32];
  const float4* wrow = reinterpret_cast<const float4*>(W_hh + (size_t)g * Hh);
#pragma unroll
  for (int i = 0; i < 32; ++i) w4[i] = wrow[i];

  float c = 0.f;
  if (g < Hh) {
    if (t0 == 0) {
      h_lds[g] = 0.f;
    } else {
      h_lds[g] = hstate[b * Hh + g];
      c = cstate[b * Hh + g];
    }
  }
  __syncthreads();

  const float* xwb = xw + (size_t)b * TC * G;
  float xw_cur = xwb[g];
  float xw_nxt = (TC > 1) ? xwb[G + g] : 0.f;

  for (int tl = 0; tl < TC; ++tl) {
    // prefetch t+2 (hides HBM/L3 latency under the dot + activations)
    float xw_pre = 0.f;
    if (tl + 2 < TC) xw_pre = xwb[(size_t)(tl + 2) * G + g];

    // gate_g = xw + W_hh[g,:] . h ; 4 accumulators break the dep chain
    float a0 = xw_cur, a1 = 0.f, a2 = 0.f, a3 = 0.f;
#pragma unroll
    for (int kk = 0; kk < 32; ++kk) {
      float4 hv = *reinterpret_cast<const float4*>(&h_lds[kk * 4]);
      a0 = fmaf(w4[kk].x, hv.x, a0);
      a1 = fmaf(w4[kk].y, hv.y, a1);
      a2 = fmaf(w4[kk].z, hv.z, a2);
      a3 = fmaf(w4[kk].w, hv.w, a3);
    }
    float gate = (a0 + a1) + (a2 + a3);
    // torch gate order i,f,g,o: sel = g>>7; only sel==2 is tanh
    float v = ((g >> 7) == 2) ? ftanh_(gate) : fsig(gate);
    gl[g] = v;
    __syncthreads();  // gl visible; all h_lds reads of this step done

    if (g < Hh) {
      float i_ = gl[g], f_ = gl[Hh + g], gg = gl[2 * Hh + g], o_ = gl[3 * Hh + g];
      c = fmaf(f_, c, i_ * gg);
      h_lds[g] = o_ * ftanh_(c);
    }
    __syncthreads();  // h_lds ready for next step

    xw_cur = xw_nxt;
    xw_nxt = xw_pre;
  }

  if (g < Hh) {
    hstate[b * Hh + g] = h_lds[g];
    cstate[b * Hh + g] = c;
  }

  // Final FC fused into the last chunk (tiny: 256x4)
  if (t0 + TC == Tt && g < 4) {
    float s = fc_b[g];
    for (int j = 0; j < Hh; ++j) s = fmaf(h_lds[j], fc_w[g * Hh + j], s);
    out[b * 4 + g] = s;
  }
}

// ---------------------------------------------------------------------------
template <int TC>
static void run_chunks(const float* x, const float* gamma, const float* beta,
                       const float* rmean, const float* rvar,
                       const float* W_ih, const float* W_hh,
                       const float* b_ih, const float* b_hh,
                       const float* fc_w, const float* fc_b, float* out,
                       void* d_ws, hipStream_t stream) {
  float* xw = reinterpret_cast<float*>(d_ws);
  float* hst = xw + (size_t)Bb * TC * G;
  float* cst = hst + (size_t)Bb * Hh;
  for (int t0 = 0; t0 < Tt; t0 += TC) {
    dim3 g1(Bb * TC / 64, G / 64);
    k1_gemm<TC><<<g1, dim3(256), 0, stream>>>(x, gamma, beta, rmean, rvar,
                                              W_ih, b_ih, b_hh, xw, t0);
    k2_lstm<TC><<<dim3(Bb), dim3(512), 0, stream>>>(xw, W_hh, hst, cst, fc_w,
                                                    fc_b, out, t0);
  }
}

extern "C" void kernel_launch(void* const* d_in, const int* in_sizes, int n_in,
                              void* d_out, int out_size, void* d_ws,
                              size_t ws_size, hipStream_t stream) {
  const float* x     = (const float*)d_in[0];
  const float* gamma = (const float*)d_in[1];
  const float* beta  = (const float*)d_in[2];
  const float* rmean = (const float*)d_in[3];
  const float* rvar  = (const float*)d_in[4];
  const float* W_ih  = (const float*)d_in[5];
  const float* W_hh  = (const float*)d_in[6];
  const float* b_ih  = (const float*)d_in[7];
  const float* b_hh  = (const float*)d_in[8];
  const float* fc_w  = (const float*)d_in[9];
  const float* fc_b  = (const float*)d_in[10];
  float* out = (float*)d_out;

  auto need = [](int tc) {
    return (size_t)Bb * tc * G * 4 + 2 * (size_t)Bb * Hh * 4;
  };

  if (ws_size >= need(250)) {
    run_chunks<250>(x, gamma, beta, rmean, rvar, W_ih, W_hh, b_ih, b_hh, fc_w,
                    fc_b, out, d_ws, stream);
  } else if (ws_size >= need(125)) {
    run_chunks<125>(x, gamma, beta, rmean, rvar, W_ih, W_hh, b_ih, b_hh, fc_w,
                    fc_b, out, d_ws, stream);
  } else if (ws_size >= need(50)) {
    run_chunks<50>(x, gamma, beta, rmean, rvar, W_ih, W_hh, b_ih, b_hh, fc_w,
                   fc_b, out, d_ws, stream);
  } else {
    run_chunks<10>(x, gamma, beta, rmean, rvar, W_ih, W_hh, b_ih, b_hh, fc_w,
                   fc_b, out, d_ws, stream);
  }
}

// Round 3
// 1136.767 us; speedup vs baseline: 1.3419x; 1.3419x over previous
//
#include <hip/hip_runtime.h>
#include <cstdint>

// Problem constants
constexpr int Cc = 95;    // input channels
constexpr int Hh = 128;   // hidden
constexpr int G  = 512;   // 4*H gates
constexpr int Bb = 256;   // batch
constexpr int Tt = 1000;  // timesteps
#define EPSBN 1e-5f

typedef _Float16 half2v __attribute__((ext_vector_type(2)));

// cvt_pkrtz returns __fp16x2 on hipcc; bit_cast to the _Float16x2 the fdot2
// builtin wants (identical IEEE-half bit layout).
__device__ __forceinline__ half2v pkrtz(float a, float b) {
  return __builtin_bit_cast(half2v, __builtin_amdgcn_cvt_pkrtz(a, b));
}

__device__ __forceinline__ float fdot2(half2v a, half2v b, float c) {
#if __has_builtin(__builtin_amdgcn_fdot2)
  return __builtin_amdgcn_fdot2(a, b, c, false);
#else
  return fmaf((float)a[0], (float)b[0], fmaf((float)a[1], (float)b[1], c));
#endif
}

// ---------------------------------------------------------------------------
// K1: xw[m][g] = BN(x[b, t0+tl, :]) . W_ih[g, :] + (b_ih[g] + b_hh[g])
//     f16-pair inputs, fp32 accumulate via v_dot2. K=95 -> 48 pairs (padded).
// ---------------------------------------------------------------------------
template <int TC>
__global__ __launch_bounds__(256)
void k1_gemm(const float* __restrict__ x, const float* __restrict__ gamma,
             const float* __restrict__ beta, const float* __restrict__ rmean,
             const float* __restrict__ rvar, const float* __restrict__ W_ih,
             const float* __restrict__ b_ih, const float* __restrict__ b_hh,
             float* __restrict__ xw, int t0) {
  constexpr int KP = 48;  // ceil(95/2)
  // row-major [row][pair], +1 pad -> row stride 49 dwords (odd): W-reads are
  // 2-way bank aliased (free), A-reads are 4-addr broadcast.
  __shared__ half2v As2[64][KP + 1];
  __shared__ half2v Ws2[64][KP + 1];
  __shared__ float scl[Cc], sft[Cc];

  const int tid = threadIdx.x;
  if (tid < Cc) {
    float s = gamma[tid] * rsqrtf(rvar[tid] + EPSBN);
    scl[tid] = s;
    sft[tid] = beta[tid] - rmean[tid] * s;
  }
  __syncthreads();

  const int row0 = blockIdx.x * 64;  // chunk-local xn row
  const int col0 = blockIdx.y * 64;  // gate column

  // Stage A (BN applied, packed f16 pairs) and W (packed). Lanes walk kp
  // consecutively -> LDS writes stride-1 (conflict-free), global reads
  // contiguous within each 380B row.
  for (int idx = tid; idx < 64 * KP; idx += 256) {
    int r = idx / KP;
    int kp = idx - r * KP;
    int c0 = 2 * kp;
    int m = row0 + r;
    int b = m / TC;
    int tl = m - b * TC;
    const float* xr = x + ((size_t)b * Tt + t0 + tl) * Cc;
    float a0 = xr[c0] * scl[c0] + sft[c0];
    float a1 = (c0 + 1 < Cc) ? xr[c0 + 1] * scl[c0 + 1] + sft[c0 + 1] : 0.f;
    As2[r][kp] = pkrtz(a0, a1);
    const float* wr = W_ih + (size_t)(col0 + r) * Cc;
    float w0 = wr[c0];
    float w1 = (c0 + 1 < Cc) ? wr[c0 + 1] : 0.f;
    Ws2[r][kp] = pkrtz(w0, w1);
  }
  __syncthreads();

  const int tx = tid & 15, ty = tid >> 4;
  const int ai = ty * 4, wi = tx * 4;
  float acc[4][4] = {};

#pragma unroll 6
  for (int kp = 0; kp < KP; ++kp) {
    half2v a0 = As2[ai + 0][kp], a1 = As2[ai + 1][kp];
    half2v a2 = As2[ai + 2][kp], a3 = As2[ai + 3][kp];
    half2v w0 = Ws2[wi + 0][kp], w1 = Ws2[wi + 1][kp];
    half2v w2 = Ws2[wi + 2][kp], w3 = Ws2[wi + 3][kp];
    acc[0][0] = fdot2(a0, w0, acc[0][0]); acc[0][1] = fdot2(a0, w1, acc[0][1]);
    acc[0][2] = fdot2(a0, w2, acc[0][2]); acc[0][3] = fdot2(a0, w3, acc[0][3]);
    acc[1][0] = fdot2(a1, w0, acc[1][0]); acc[1][1] = fdot2(a1, w1, acc[1][1]);
    acc[1][2] = fdot2(a1, w2, acc[1][2]); acc[1][3] = fdot2(a1, w3, acc[1][3]);
    acc[2][0] = fdot2(a2, w0, acc[2][0]); acc[2][1] = fdot2(a2, w1, acc[2][1]);
    acc[2][2] = fdot2(a2, w2, acc[2][2]); acc[2][3] = fdot2(a2, w3, acc[2][3]);
    acc[3][0] = fdot2(a3, w0, acc[3][0]); acc[3][1] = fdot2(a3, w1, acc[3][1]);
    acc[3][2] = fdot2(a3, w2, acc[3][2]); acc[3][3] = fdot2(a3, w3, acc[3][3]);
  }

  float bi0 = b_ih[col0 + wi + 0] + b_hh[col0 + wi + 0];
  float bi1 = b_ih[col0 + wi + 1] + b_hh[col0 + wi + 1];
  float bi2 = b_ih[col0 + wi + 2] + b_hh[col0 + wi + 2];
  float bi3 = b_ih[col0 + wi + 3] + b_hh[col0 + wi + 3];
#pragma unroll
  for (int i = 0; i < 4; ++i) {
    size_t m = (size_t)(row0 + ai + i);
    float4 v = make_float4(acc[i][0] + bi0, acc[i][1] + bi1,
                           acc[i][2] + bi2, acc[i][3] + bi3);
    *reinterpret_cast<float4*>(&xw[m * G + col0 + wi]) = v;
  }
}

// ---------------------------------------------------------------------------
// K2: per-batch LSTM recurrence. 256 blocks x 512 threads.
// tid = 4*j + q : unit j in [0,128), gate q in {i,f,g,o}. The 4 gates of a
// unit live in adjacent lanes -> i/f/g/o exchange via shfl_xor (no barrier).
// h kept packed-f16 in double-buffered LDS -> ONE barrier per step.
// W_hh row (f16 pairs) lives in 64 VGPRs per thread; gate dot = 64 v_dot2.
// ---------------------------------------------------------------------------
template <int TC>
__global__ __launch_bounds__(512)
void k2_lstm(const float* __restrict__ xw, const float* __restrict__ W_hh,
             float* __restrict__ hstate, float* __restrict__ cstate,
             const float* __restrict__ fc_w, const float* __restrict__ fc_b,
             float* __restrict__ out, int t0) {
  __shared__ __align__(16) half2v h2lds[2][Hh / 2];
  __shared__ float h32[Hh];

  const int b = blockIdx.x;
  const int tid = threadIdx.x;
  const int j = tid >> 2;        // hidden unit
  const int q = tid & 3;         // gate type (torch order i,f,g,o)
  const int r = q * Hh + j;      // W_hh / xw gate-row index
  const bool isg = (q == 2);     // tanh gate

  // W_hh row -> packed f16 pairs in registers (L2/L3 resident, 256 KB total)
  half2v w2[64];
  {
    const float2* wr = reinterpret_cast<const float2*>(W_hh + (size_t)r * Hh);
#pragma unroll
    for (int i = 0; i < 64; ++i) {
      float2 t = wr[i];
      w2[i] = pkrtz(t.x, t.y);
    }
  }

  float creg = 0.f, hreg = 0.f;
  if (t0 == 0) {
    if (tid < Hh / 2) h2lds[0][tid] = half2v{(_Float16)0, (_Float16)0};
  } else {
    if (q == 0) {
      hreg = hstate[b * Hh + j];
      creg = cstate[b * Hh + j];
    }
    if (tid < Hh / 2)
      h2lds[0][tid] = pkrtz(hstate[b * Hh + 2 * tid],
                            hstate[b * Hh + 2 * tid + 1]);
  }
  __syncthreads();

  const float* xwb = xw + (size_t)b * TC * G;
  float xw_cur = xwb[r];
  float xw_nxt = (TC > 1) ? xwb[G + r] : 0.f;

  for (int tl = 0; tl < TC; ++tl) {
    const int rb = tl & 1;
    // prefetch t+2
    float xw_pre = 0.f;
    if (tl + 2 < TC) xw_pre = xwb[(size_t)(tl + 2) * G + r];

    // gate = xw + W_hh[r,:] . h   (64 dot2, 4 accumulator chains)
    float a0 = xw_cur, a1 = 0.f, a2 = 0.f, a3 = 0.f;
    const uint4* hp = reinterpret_cast<const uint4*>(h2lds[rb]);
#pragma unroll
    for (int kk = 0; kk < 16; ++kk) {
      uint4 hv = hp[kk];  // broadcast read (uniform address)
      a0 = fdot2(w2[4 * kk + 0], __builtin_bit_cast(half2v, hv.x), a0);
      a1 = fdot2(w2[4 * kk + 1], __builtin_bit_cast(half2v, hv.y), a1);
      a2 = fdot2(w2[4 * kk + 2], __builtin_bit_cast(half2v, hv.z), a2);
      a3 = fdot2(w2[4 * kk + 3], __builtin_bit_cast(half2v, hv.w), a3);
    }
    float gate = (a0 + a1) + (a2 + a3);

    // branchless activation: sigmoid for q!=2, tanh(x)=2*sigmoid(2x)-1 for q==2
    float y = isg ? 2.f * gate : gate;
    y = fminf(30.f, fmaxf(-30.f, y));
    float e = __expf(-y);
    float s = __fdividef(1.f, 1.f + e);
    float v = isg ? fmaf(2.f, s, -1.f) : s;

    // quad exchange: lane q sees (v, v^1, v^2, v^3) = gates (q, q^1, q^2, q^3)
    float vb = __shfl_xor(v, 1);
    float vc = __shfl_xor(v, 2);
    float vd = __shfl_xor(vb, 2);

    if (q == 0) {  // v=i, vb=f, vc=g, vd=o
      creg = fmaf(vb, creg, v * vc);
      float yc = fminf(30.f, fmaxf(-30.f, 2.f * creg));
      float ec = __expf(yc);
      float th = __fdividef(ec - 1.f, ec + 1.f);  // tanh(c)
      hreg = vd * th;
    }
    // pack (h_j, h_{j+1}) -> write buffer; shfl outside divergence
    float hn = __shfl_down(hreg, 4);
    if ((tid & 7) == 0)
      h2lds[rb ^ 1][j >> 1] = pkrtz(hreg, hn);
    __syncthreads();  // single barrier per step (double-buffered h)

    xw_cur = xw_nxt;
    xw_nxt = xw_pre;
  }

  if (q == 0) {
    hstate[b * Hh + j] = hreg;
    cstate[b * Hh + j] = creg;
    h32[j] = hreg;
  }
  __syncthreads();

  // Final FC fused into the last chunk (256x4)
  if (t0 + TC == Tt && tid < 4) {
    float s = fc_b[tid];
    for (int jj = 0; jj < Hh; ++jj) s = fmaf(h32[jj], fc_w[tid * Hh + jj], s);
    out[b * 4 + tid] = s;
  }
}

// ---------------------------------------------------------------------------
template <int TC>
static void run_chunks(const float* x, const float* gamma, const float* beta,
                       const float* rmean, const float* rvar,
                       const float* W_ih, const float* W_hh,
                       const float* b_ih, const float* b_hh,
                       const float* fc_w, const float* fc_b, float* out,
                       void* d_ws, hipStream_t stream) {
  float* xw = reinterpret_cast<float*>(d_ws);
  float* hst = xw + (size_t)Bb * TC * G;
  float* cst = hst + (size_t)Bb * Hh;
  for (int t0 = 0; t0 < Tt; t0 += TC) {
    dim3 g1(Bb * TC / 64, G / 64);
    k1_gemm<TC><<<g1, dim3(256), 0, stream>>>(x, gamma, beta, rmean, rvar,
                                              W_ih, b_ih, b_hh, xw, t0);
    k2_lstm<TC><<<dim3(Bb), dim3(512), 0, stream>>>(xw, W_hh, hst, cst, fc_w,
                                                    fc_b, out, t0);
  }
}

extern "C" void kernel_launch(void* const* d_in, const int* in_sizes, int n_in,
                              void* d_out, int out_size, void* d_ws,
                              size_t ws_size, hipStream_t stream) {
  const float* x     = (const float*)d_in[0];
  const float* gamma = (const float*)d_in[1];
  const float* beta  = (const float*)d_in[2];
  const float* rmean = (const float*)d_in[3];
  const float* rvar  = (const float*)d_in[4];
  const float* W_ih  = (const float*)d_in[5];
  const float* W_hh  = (const float*)d_in[6];
  const float* b_ih  = (const float*)d_in[7];
  const float* b_hh  = (const float*)d_in[8];
  const float* fc_w  = (const float*)d_in[9];
  const float* fc_b  = (const float*)d_in[10];
  float* out = (float*)d_out;

  auto need = [](int tc) {
    return (size_t)Bb * tc * G * 4 + 2 * (size_t)Bb * Hh * 4;
  };

  if (ws_size >= need(250)) {
    run_chunks<250>(x, gamma, beta, rmean, rvar, W_ih, W_hh, b_ih, b_hh, fc_w,
                    fc_b, out, d_ws, stream);
  } else if (ws_size >= need(125)) {
    run_chunks<125>(x, gamma, beta, rmean, rvar, W_ih, W_hh, b_ih, b_hh, fc_w,
                    fc_b, out, d_ws, stream);
  } else if (ws_size >= need(50)) {
    run_chunks<50>(x, gamma, beta, rmean, rvar, W_ih, W_hh, b_ih, b_hh, fc_w,
                   fc_b, out, d_ws, stream);
  } else {
    run_chunks<10>(x, gamma, beta, rmean, rvar, W_ih, W_hh, b_ih, b_hh, fc_w,
                   fc_b, out, d_ws, stream);
  }
}